// Round 9
// baseline (1355.809 us; speedup 1.0000x reference)
//
#include <hip/hip_runtime.h>
#include <math.h>

// Problem constants
#define BB    64
#define SS    512
#define HH    256
#define HH2   512
#define TMAXX 513
#define NTOP  5
#define EPSF  1e-7f

#if defined(__has_builtin)
#if __has_builtin(__builtin_amdgcn_sdot4)
#define HAVE_SDOT4 1
#endif
#endif

__device__ __forceinline__ int dot4i8_(unsigned a, int b, int c) {
#ifdef HAVE_SDOT4
  return __builtin_amdgcn_sdot4((int)a, b, c, false);
#else
  int acc = c;
#pragma unroll
  for (int j = 0; j < 4; ++j) {
    int av = (int)(signed char)(a >> (8 * j));
    int bv = (int)(signed char)(((unsigned)b) >> (8 * j));
    acc += av * bv;
  }
  return acc;
#endif
}

// Canonical GCN wave64 sum reduction via DPP (VALU-latency, no LDS ops):
// row_shr 1/2/4/8 within 16-lane rows, row_bcast15/31 to merge rows,
// v_readlane lane 63 -> SGPR broadcast to all lanes.
__device__ __forceinline__ float dpp_sum64(float x) {
  int t;
  t = __builtin_amdgcn_update_dpp(0, __builtin_bit_cast(int, x), 0x111, 0xf, 0xf, true);
  x += __builtin_bit_cast(float, t);
  t = __builtin_amdgcn_update_dpp(0, __builtin_bit_cast(int, x), 0x112, 0xf, 0xf, true);
  x += __builtin_bit_cast(float, t);
  t = __builtin_amdgcn_update_dpp(0, __builtin_bit_cast(int, x), 0x114, 0xf, 0xe, true);
  x += __builtin_bit_cast(float, t);
  t = __builtin_amdgcn_update_dpp(0, __builtin_bit_cast(int, x), 0x118, 0xf, 0xc, true);
  x += __builtin_bit_cast(float, t);
  t = __builtin_amdgcn_update_dpp(0, __builtin_bit_cast(int, x), 0x142, 0xa, 0xf, true);
  x += __builtin_bit_cast(float, t);
  t = __builtin_amdgcn_update_dpp(0, __builtin_bit_cast(int, x), 0x143, 0xc, 0xf, true);
  x += __builtin_bit_cast(float, t);
  return __builtin_bit_cast(float, __builtin_amdgcn_readlane(__builtin_bit_cast(int, x), 63));
}

// ws layout:
//  [0, 512KB)     int8 W_hh packed: uint4 at (d*16 + kq4)*1024 + row
//  [1MB, 1MB+8KB) per-gate-row dequant scales, [d*1024 + row]
//  [4MB, 68MB)    hcomb [64 rows][512 steps][512 elems] f32 (lstm out, read-only for attn)

// -------------------------------------------------------------------------
__global__ void init_kernel(const float* __restrict__ Whh_f, const float* __restrict__ Whh_b,
                            uint4* __restrict__ wq, float* __restrict__ scales) {
  int t = blockIdx.x * blockDim.x + threadIdx.x;
  if (t >= 2048) return;
  int d = t >> 10, row = t & 1023;
  const float* src = (d ? Whh_b : Whh_f) + (size_t)row * HH;
  float m = 1e-20f;
  for (int k = 0; k < HH; ++k) m = fmaxf(m, fabsf(src[k]));
  float inv = 127.f / m;
  scales[t] = m * (1.f / 16129.f);
  for (int kq4 = 0; kq4 < 16; ++kq4) {
    unsigned u[4];
#pragma unroll
    for (int w = 0; w < 4; ++w) {
      unsigned uu = 0;
#pragma unroll
      for (int j = 0; j < 4; ++j) {
        float q = rintf(src[kq4 * 16 + w * 4 + j] * inv);
        q = fminf(fmaxf(q, -127.f), 127.f);
        uu |= ((unsigned)(((int)q) & 0xff)) << (8 * j);
      }
      u[w] = uu;
    }
    wq[(size_t)(d * 16 + kq4) * 1024 + row] = make_uint4(u[0], u[1], u[2], u[3]);
  }
}

// -------------------------------------------------------------------------
// LSTM: 128 blocks = (row r = blk>>1, dir d = blk&1), 1024 threads = 16 waves
// (4 waves/SIMD TLP). Thread tid owns ONE gate row: 16 uint4 of int8 weights
// PINNED in VGPRs via empty asm (round 7's VGPR_Count=48 proved the compiler
// rematerialized the loads inside the loop -> full L2 re-stream every step).
// Cell update is done by ALL threads (c replicated per gate-thread, bit-
// identical); only gate==0 threads write h out. Two barriers/step.
__global__ __launch_bounds__(1024, 4)
void lstm_kernel(const float* __restrict__ x,
                 const float* __restrict__ wihf, const float* __restrict__ bf,
                 const float* __restrict__ wihb, const float* __restrict__ bb_,
                 const uint4* __restrict__ wq, const float* __restrict__ scales,
                 float* __restrict__ hcomb) {
  const int r    = blockIdx.x >> 1;
  const int d    = blockIdx.x & 1;
  const int tid  = threadIdx.x;       // gate row 0..1023
  const int gate = tid >> 8;          // 0=i,1=f,2=g,3=o (wave-uniform)
  const int e    = tid & 255;

  __shared__ float x_lds[SS];         // 2 KB
  __shared__ float gact[1024];        // activated gates, 4 KB
  __shared__ int   hbuf[2][64];       // double-buffered int8 h (256 each)

  for (int t = tid; t < SS; t += 1024) x_lds[t] = x[(size_t)r * SS + t];
  if (tid < 64) hbuf[0][tid] = 0;

  const float wihv = d ? wihb[tid] : wihf[tid];
  const float bv   = d ? bb_[tid]  : bf[tid];
  const float sc   = scales[d * 1024 + tid];

  uint4 w[16];
  {
    const uint4* wb = wq + (size_t)(d * 16) * 1024 + tid;
#pragma unroll
    for (int q = 0; q < 16; ++q) w[q] = wb[(size_t)q * 1024];
  }
  // Pin weights in registers: values "defined" by asm cannot be
  // rematerialized as re-loads inside the loop.
#pragma unroll
  for (int q = 0; q < 16; ++q)
    asm volatile("" : "+v"(w[q].x), "+v"(w[q].y), "+v"(w[q].z), "+v"(w[q].w));

  float c = 0.f;                      // cell state (replicated per gate-thread)
  float* hout = hcomb + (size_t)r * SS * HH2 + d * HH;
  __syncthreads();

  int cur = 0;
  for (int i = 0; i < SS; ++i) {
    const int4* hp = (const int4*)hbuf[cur];
    int a = 0;
#pragma unroll
    for (int q = 0; q < 16; ++q) {
      int4 h4 = hp[q];                // uniform address -> LDS broadcast
      a = dot4i8_(w[q].x, h4.x, a);
      a = dot4i8_(w[q].y, h4.y, a);
      a = dot4i8_(w[q].z, h4.z, a);
      a = dot4i8_(w[q].w, h4.w, a);
    }
    float xv = x_lds[d ? (SS - 1 - i) : i];
    float gv = (float)a * sc + fmaf(xv, wihv, bv);
    gact[tid] = (gate == 2) ? tanhf(gv) : 1.f / (1.f + expf(-gv));
    __syncthreads();
    float ig = gact[e];
    float fg = gact[HH + e];
    float gg = gact[2 * HH + e];
    float og = gact[3 * HH + e];
    c = fg * c + ig * gg;
    float hn = og * tanhf(c);
    if (gate == 0) {
      hout[(size_t)i * HH2 + e] = hn;
      ((signed char*)hbuf[cur ^ 1])[e] = (signed char)(int)rintf(hn * 127.f);
    }
    cur ^= 1;
    __syncthreads();
  }
}

// -------------------------------------------------------------------------
// Attention: ONE WAVE per batch row (64 blocks x 64 lanes). Lane l owns elems
// A=[4l,4l+4) and B=[256+4l,256+4l+4). All reductions via DPP (VALU-latency)
// + readlane broadcast -> every lane keeps bit-identical replicated top-5
// (value,slot) state and the 5 cached h_new rows in registers (an evicted
// index never re-enters; the inserted row is always the just-computed h_new).
// hc is prefetched FOUR steps ahead (static ring via x4 unroll) so the L3
// load latency sits ~3 steps off the critical chain. No barriers, no LDS in
// the chain (tw history only, for the final attn_w output).
__global__ __launch_bounds__(64, 1)
void attn_kernel(const float* __restrict__ w_t, const float* __restrict__ hcomb,
                 float* __restrict__ out) {
  const int b = blockIdx.x;
  const int l = threadIdx.x;          // 0..63
  const float* hrow = hcomb + (size_t)b * SS * HH2;

  __shared__ float tw_l[TMAXX];       // tw[t] history (final attn_w only)

  const float4 w1a = *(const float4*)(w_t + 4 * l);
  const float4 w1b = *(const float4*)(w_t + HH + 4 * l);
  const float4 w2a = *(const float4*)(w_t + HH2 + 4 * l);
  const float4 w2b = *(const float4*)(w_t + HH2 + HH + 4 * l);

  float t5v[5] = {0.f, -1e30f, -1e30f, -1e30f, -1e30f};
  int   t5s[5] = {0, 1, 2, 3, 4};
  int   t5cnt  = 1;                   // entry 0 = (t=0, zero row)
  float4 z4 = make_float4(0.f, 0.f, 0.f, 0.f);
  float4 sA0 = z4, sA1 = z4, sA2 = z4, sA3 = z4, sA4 = z4;
  float4 sB0 = z4, sB1 = z4, sB2 = z4, sB3 = z4, sB4 = z4;
  if (l == 0) tw_l[0] = 0.f;

  float tw5 = 0.f, inv = 0.f;

  // prefetch ring, depth 4 (SS % 4 == 0; all indexing static)
  float4 a0 = *(const float4*)(hrow + 0 * HH2 + 4 * l);
  float4 b0 = *(const float4*)(hrow + 0 * HH2 + HH + 4 * l);
  float4 a1 = *(const float4*)(hrow + 1 * HH2 + 4 * l);
  float4 b1 = *(const float4*)(hrow + 1 * HH2 + HH + 4 * l);
  float4 a2 = *(const float4*)(hrow + 2 * HH2 + 4 * l);
  float4 b2 = *(const float4*)(hrow + 2 * HH2 + HH + 4 * l);
  float4 a3 = *(const float4*)(hrow + 3 * HH2 + 4 * l);
  float4 b3 = *(const float4*)(hrow + 3 * HH2 + HH + 4 * l);

  auto step = [&](float4& ha, float4& hb, int i) {
    // ---- per-rank weights (uniform across lanes)
    float wr[5];
    if (i >= NTOP) {
      tw5 = t5v[4];
      float rk0 = fmaxf(t5v[0] - tw5 - EPSF, 0.f);
      float rk1 = fmaxf(t5v[1] - tw5 - EPSF, 0.f);
      float rk2 = fmaxf(t5v[2] - tw5 - EPSF, 0.f);
      float rk3 = fmaxf(t5v[3] - tw5 - EPSF, 0.f);
      inv = 1.f / (rk0 + rk1 + rk2 + rk3 + EPSF);
      wr[0] = rk0 * inv; wr[1] = rk1 * inv; wr[2] = rk2 * inv; wr[3] = rk3 * inv;
      wr[4] = 0.f;
    } else {
      float sv = tanhf(ha.x) * w1a.x + tanhf(ha.y) * w1a.y +
                 tanhf(ha.z) * w1a.z + tanhf(ha.w) * w1a.w +
                 tanhf(hb.x) * w1b.x + tanhf(hb.y) * w1b.y +
                 tanhf(hb.z) * w1b.z + tanhf(hb.w) * w1b.w;
      float s = dpp_sum64(sv);
#pragma unroll
      for (int k = 0; k < 5; ++k) wr[k] = (k < t5cnt) ? (s + t5v[k]) : 0.f;
    }
    // ---- rank -> slot weights (uniform, branch-free)
    float ws0 = 0.f, ws1 = 0.f, ws2 = 0.f, ws3 = 0.f, ws4 = 0.f;
#pragma unroll
    for (int k = 0; k < 5; ++k) {
      float wv = wr[k]; int s2 = t5s[k];
      ws0 += (s2 == 0) ? wv : 0.f;
      ws1 += (s2 == 1) ? wv : 0.f;
      ws2 += (s2 == 2) ? wv : 0.f;
      ws3 += (s2 == 3) ? wv : 0.f;
      ws4 += (s2 == 4) ? wv : 0.f;
    }
    // ---- attention context from register slot cache
    float4 cxA, cxB;
    cxA.x = ws0*sA0.x + ws1*sA1.x + ws2*sA2.x + ws3*sA3.x + ws4*sA4.x;
    cxA.y = ws0*sA0.y + ws1*sA1.y + ws2*sA2.y + ws3*sA3.y + ws4*sA4.y;
    cxA.z = ws0*sA0.z + ws1*sA1.z + ws2*sA2.z + ws3*sA3.z + ws4*sA4.z;
    cxA.w = ws0*sA0.w + ws1*sA1.w + ws2*sA2.w + ws3*sA3.w + ws4*sA4.w;
    cxB.x = ws0*sB0.x + ws1*sB1.x + ws2*sB2.x + ws3*sB3.x + ws4*sB4.x;
    cxB.y = ws0*sB0.y + ws1*sB1.y + ws2*sB2.y + ws3*sB3.y + ws4*sB4.y;
    cxB.z = ws0*sB0.z + ws1*sB1.z + ws2*sB2.z + ws3*sB3.z + ws4*sB4.z;
    cxB.w = ws0*sB0.w + ws1*sB1.w + ws2*sB2.w + ws3*sB3.w + ws4*sB4.w;
    // ---- h_new and v = tanh(h_new).w2
    float4 hnA, hnB;
    hnA.x = ha.x + cxA.x; hnA.y = ha.y + cxA.y; hnA.z = ha.z + cxA.z; hnA.w = ha.w + cxA.w;
    hnB.x = hb.x + cxB.x; hnB.y = hb.y + cxB.y; hnB.z = hb.z + cxB.z; hnB.w = hb.w + cxB.w;
    float pv = tanhf(hnA.x) * w2a.x + tanhf(hnA.y) * w2a.y +
               tanhf(hnA.z) * w2a.z + tanhf(hnA.w) * w2a.w +
               tanhf(hnB.x) * w2b.x + tanhf(hnB.y) * w2b.y +
               tanhf(hnB.z) * w2b.z + tanhf(hnB.w) * w2b.w;
    float v = dpp_sum64(pv);
    if (l == 0) tw_l[i + 1] = v;
    // ---- outputs at the last step (i = SS-1 is sparse: tw5/inv valid)
    if (i == SS - 1) {
      *(float4*)(out + (size_t)b * HH2 + 4 * l)      = cxA;
      *(float4*)(out + (size_t)b * HH2 + HH + 4 * l) = cxB;
      float* ow = out + (size_t)BB * HH2 + (size_t)b * SS;
#pragma unroll
      for (int j = 0; j < 8; ++j) {
        int t = j * 64 + l;
        float rr = tw_l[t] - tw5 - EPSF;
        ow[t] = rr > 0.f ? rr * inv : 0.f;
      }
      return;
    }
    // ---- replicated top-5 insert (uniform); update slot cache
    bool full = (t5cnt >= 5);
    bool ins  = !full || (v > t5v[4]);
    if (ins) {
      int p    = full ? 4 : t5cnt;
      int slot = full ? t5s[4] : t5cnt;
#pragma unroll
      for (int k = 0; k < 5; ++k) if (k == p) { t5v[k] = v; t5s[k] = slot; }
      if (slot == 0)      { sA0 = hnA; sB0 = hnB; }
      else if (slot == 1) { sA1 = hnA; sB1 = hnB; }
      else if (slot == 2) { sA2 = hnA; sB2 = hnB; }
      else if (slot == 3) { sA3 = hnA; sB3 = hnB; }
      else                { sA4 = hnA; sB4 = hnB; }
      if (!full) ++t5cnt;
#pragma unroll
      for (int k = 4; k >= 1; --k) {
        bool sw = (k <= p) && (t5v[k] > t5v[k - 1]);
        float v0 = t5v[k - 1], v1 = t5v[k];
        int   s0 = t5s[k - 1], s1 = t5s[k];
        t5v[k] = sw ? v0 : v1;  t5v[k - 1] = sw ? v1 : v0;
        t5s[k] = sw ? s0 : s1;  t5s[k - 1] = sw ? s1 : s0;
      }
    }
    // ---- prefetch step i+4 into this buffer (3 steps of slack)
    if (i + 4 < SS) {
      ha = *(const float4*)(hrow + (size_t)(i + 4) * HH2 + 4 * l);
      hb = *(const float4*)(hrow + (size_t)(i + 4) * HH2 + HH + 4 * l);
    }
  };

  for (int i = 0; i < SS; i += 4) {
    step(a0, b0, i);
    step(a1, b1, i + 1);
    step(a2, b2, i + 2);
    step(a3, b3, i + 3);
  }
}

// -------------------------------------------------------------------------
extern "C" void kernel_launch(void* const* d_in, const int* in_sizes, int n_in,
                              void* d_out, int out_size, void* d_ws, size_t ws_size,
                              hipStream_t stream) {
  const float* x     = (const float*)d_in[0];
  const float* Wih_f = (const float*)d_in[1];
  const float* Whh_f = (const float*)d_in[2];
  const float* b_f   = (const float*)d_in[3];
  const float* Wih_b = (const float*)d_in[4];
  const float* Whh_b = (const float*)d_in[5];
  const float* b_b   = (const float*)d_in[6];
  const float* w_t   = (const float*)d_in[7];
  float* out = (float*)d_out;

  char* ws = (char*)d_ws;
  uint4*  wq     = (uint4*)ws;                      // 512 KB int8 weights
  float*  scales = (float*)(ws + (1 << 20));        // 8 KB
  float*  hcomb  = (float*)(ws + (4 << 20));        // 64 MB

  init_kernel<<<8, 256, 0, stream>>>(Whh_f, Whh_b, wq, scales);
  lstm_kernel<<<2 * BB, 1024, 0, stream>>>(x, Wih_f, b_f, Wih_b, b_b,
                                           wq, scales, hcomb);
  attn_kernel<<<BB, 64, 0, stream>>>(w_t, hcomb, out);
}

// Round 11
// 1171.697 us; speedup vs baseline: 1.1571x; 1.1571x over previous
//
#include <hip/hip_runtime.h>
#include <math.h>

// Problem constants
#define BB    64
#define SS    512
#define HH    256
#define HH2   512
#define TMAXX 513
#define NTOP  5
#define EPSF  1e-7f

#if defined(__has_builtin)
#if __has_builtin(__builtin_amdgcn_sdot4)
#define HAVE_SDOT4 1
#endif
#endif

__device__ __forceinline__ int dot4i8_(unsigned a, int b, int c) {
#ifdef HAVE_SDOT4
  return __builtin_amdgcn_sdot4((int)a, b, c, false);
#else
  int acc = c;
#pragma unroll
  for (int j = 0; j < 4; ++j) {
    int av = (int)(signed char)(a >> (8 * j));
    int bv = (int)(signed char)(((unsigned)b) >> (8 * j));
    acc += av * bv;
  }
  return acc;
#endif
}

// Canonical GCN wave64 sum reduction via DPP + readlane broadcast.
__device__ __forceinline__ float dpp_sum64(float x) {
  int t;
  t = __builtin_amdgcn_update_dpp(0, __builtin_bit_cast(int, x), 0x111, 0xf, 0xf, true);
  x += __builtin_bit_cast(float, t);
  t = __builtin_amdgcn_update_dpp(0, __builtin_bit_cast(int, x), 0x112, 0xf, 0xf, true);
  x += __builtin_bit_cast(float, t);
  t = __builtin_amdgcn_update_dpp(0, __builtin_bit_cast(int, x), 0x114, 0xf, 0xe, true);
  x += __builtin_bit_cast(float, t);
  t = __builtin_amdgcn_update_dpp(0, __builtin_bit_cast(int, x), 0x118, 0xf, 0xc, true);
  x += __builtin_bit_cast(float, t);
  t = __builtin_amdgcn_update_dpp(0, __builtin_bit_cast(int, x), 0x142, 0xa, 0xf, true);
  x += __builtin_bit_cast(float, t);
  t = __builtin_amdgcn_update_dpp(0, __builtin_bit_cast(int, x), 0x143, 0xc, 0xf, true);
  x += __builtin_bit_cast(float, t);
  return __builtin_bit_cast(float, __builtin_amdgcn_readlane(__builtin_bit_cast(int, x), 63));
}

// Branch-free fast tanh: 2*sigmoid(2x)-1, NaN-safe at +/-inf.
// tanh err ~1e-6 rel — far below the int8-LSTM noise floor.
__device__ __forceinline__ float fast_tanh(float x) {
  float t = exp2f(x * -2.885390082f);                 // e^(-2x)
  return fmaf(__builtin_amdgcn_rcpf(1.f + t), 2.f, -1.f);
}

// ws layout:
//  [0, 512KB)     int8 W_hh packed: uint4 at (d*16 + kq4)*1024 + row
//  [1MB, 1MB+8KB) per-gate-row dequant scales, [d*1024 + row]
//  [4MB, 68MB)    hcomb [64 rows][512 steps][512 elems] f32 (lstm out, read-only for attn)

// -------------------------------------------------------------------------
__global__ void init_kernel(const float* __restrict__ Whh_f, const float* __restrict__ Whh_b,
                            uint4* __restrict__ wq, float* __restrict__ scales) {
  int t = blockIdx.x * blockDim.x + threadIdx.x;
  if (t >= 2048) return;
  int d = t >> 10, row = t & 1023;
  const float* src = (d ? Whh_b : Whh_f) + (size_t)row * HH;
  float m = 1e-20f;
  for (int k = 0; k < HH; ++k) m = fmaxf(m, fabsf(src[k]));
  float inv = 127.f / m;
  scales[t] = m * (1.f / 16129.f);
  for (int kq4 = 0; kq4 < 16; ++kq4) {
    unsigned u[4];
#pragma unroll
    for (int w = 0; w < 4; ++w) {
      unsigned uu = 0;
#pragma unroll
      for (int j = 0; j < 4; ++j) {
        float q = rintf(src[kq4 * 16 + w * 4 + j] * inv);
        q = fminf(fmaxf(q, -127.f), 127.f);
        uu |= ((unsigned)(((int)q) & 0xff)) << (8 * j);
      }
      u[w] = uu;
    }
    wq[(size_t)(d * 16 + kq4) * 1024 + row] = make_uint4(u[0], u[1], u[2], u[3]);
  }
}

// -------------------------------------------------------------------------
// LSTM: 128 blocks = (row r = blk>>1, dir d = blk&1), 256 threads (4 waves,
// 1 block/CU by VGPR). Thread e owns ALL FOUR gate rows of element e
// (64 uint4 int8 weights pinned in VGPRs). h-exchange per step per wave:
// ONE lane-addressed ds_read_b32 (64 lanes x 4B = whole 256-B h vector) +
// 64 v_readlane -> SGPR broadcast feeding v_dot4 directly. This removes the
// r5-r9 bottleneck: 256 uniform ds_read_b128/CU/step (~3000 cyc LDS-pipe
// floor) -> ~2 LDS instrs/wave/step. Cell update fully in-thread; one
// barrier/step (double-buffered int8 h). Integer dot order bit-identical.
__global__ __launch_bounds__(256, 1)
void lstm_kernel(const float* __restrict__ x,
                 const float* __restrict__ wihf, const float* __restrict__ bf,
                 const float* __restrict__ wihb, const float* __restrict__ bb_,
                 const uint4* __restrict__ wq, const float* __restrict__ scales,
                 float* __restrict__ hcomb) {
  const int r = blockIdx.x >> 1;
  const int d = blockIdx.x & 1;
  const int e = threadIdx.x;          // element 0..255
  const int l = e & 63;               // lane

  __shared__ float x_lds[SS];         // 2 KB
  __shared__ int   hbuf[2][64];       // double-buffered int8 h (256 B each)

  for (int t = e; t < SS; t += 256) x_lds[t] = x[(size_t)r * SS + t];
  if (e < 64) hbuf[0][e] = 0;

  float wih[4], bias[4], sc[4];
#pragma unroll
  for (int g = 0; g < 4; ++g) {
    int row = g * HH + e;
    wih[g]  = d ? wihb[row] : wihf[row];
    bias[g] = d ? bb_[row]  : bf[row];
    sc[g]   = scales[d * 1024 + row];
  }
  uint4 w0[16], w1[16], w2[16], w3[16];
#pragma unroll
  for (int q = 0; q < 16; ++q) {
    const uint4* wb = wq + (size_t)(d * 16 + q) * 1024;
    w0[q] = wb[0 * HH + e];
    w1[q] = wb[1 * HH + e];
    w2[q] = wb[2 * HH + e];
    w3[q] = wb[3 * HH + e];
  }
  // Pin: asm-defined values cannot be rematerialized as re-loads.
#pragma unroll
  for (int q = 0; q < 16; ++q) {
    asm volatile("" : "+v"(w0[q].x), "+v"(w0[q].y), "+v"(w0[q].z), "+v"(w0[q].w));
    asm volatile("" : "+v"(w1[q].x), "+v"(w1[q].y), "+v"(w1[q].z), "+v"(w1[q].w));
    asm volatile("" : "+v"(w2[q].x), "+v"(w2[q].y), "+v"(w2[q].z), "+v"(w2[q].w));
    asm volatile("" : "+v"(w3[q].x), "+v"(w3[q].y), "+v"(w3[q].z), "+v"(w3[q].w));
  }

  float c = 0.f;
  float* hout = hcomb + (size_t)r * SS * HH2 + d * HH;
  __syncthreads();

  int cur = 0;
  for (int i = 0; i < SS; ++i) {
    int hq = hbuf[cur][l];            // 1 lane-addressed ds_read_b32 per wave
    int hs[64];                       // wave-broadcast h chunks (SGPR/VGPR)
#pragma unroll
    for (int j = 0; j < 64; ++j) hs[j] = __builtin_amdgcn_readlane(hq, j);
    int a0 = 0, a1 = 0, a2 = 0, a3 = 0;
#pragma unroll
    for (int q = 0; q < 16; ++q) {
      a0 = dot4i8_(w0[q].x, hs[4 * q + 0], a0);
      a0 = dot4i8_(w0[q].y, hs[4 * q + 1], a0);
      a0 = dot4i8_(w0[q].z, hs[4 * q + 2], a0);
      a0 = dot4i8_(w0[q].w, hs[4 * q + 3], a0);
      a1 = dot4i8_(w1[q].x, hs[4 * q + 0], a1);
      a1 = dot4i8_(w1[q].y, hs[4 * q + 1], a1);
      a1 = dot4i8_(w1[q].z, hs[4 * q + 2], a1);
      a1 = dot4i8_(w1[q].w, hs[4 * q + 3], a1);
      a2 = dot4i8_(w2[q].x, hs[4 * q + 0], a2);
      a2 = dot4i8_(w2[q].y, hs[4 * q + 1], a2);
      a2 = dot4i8_(w2[q].z, hs[4 * q + 2], a2);
      a2 = dot4i8_(w2[q].w, hs[4 * q + 3], a2);
      a3 = dot4i8_(w3[q].x, hs[4 * q + 0], a3);
      a3 = dot4i8_(w3[q].y, hs[4 * q + 1], a3);
      a3 = dot4i8_(w3[q].z, hs[4 * q + 2], a3);
      a3 = dot4i8_(w3[q].w, hs[4 * q + 3], a3);
    }
    float xv = x_lds[d ? (SS - 1 - i) : i];
    float gi = (float)a0 * sc[0] + fmaf(xv, wih[0], bias[0]);
    float gf = (float)a1 * sc[1] + fmaf(xv, wih[1], bias[1]);
    float gg = (float)a2 * sc[2] + fmaf(xv, wih[2], bias[2]);
    float go = (float)a3 * sc[3] + fmaf(xv, wih[3], bias[3]);
    float ig = 1.f / (1.f + expf(-gi));
    float fg = 1.f / (1.f + expf(-gf));
    float og = 1.f / (1.f + expf(-go));
    c = fg * c + ig * tanhf(gg);
    float hn = og * tanhf(c);
    hout[(size_t)i * HH2 + e] = hn;
    ((signed char*)hbuf[cur ^ 1])[e] = (signed char)(int)rintf(hn * 127.f);
    cur ^= 1;
    __syncthreads();
  }
}

// -------------------------------------------------------------------------
// Attention: ONE WAVE per batch row (64 blocks x 64 lanes), as round 9, with
// the libm tanhf (OCML: ~40 instrs, both-path select) replaced by the 5-instr
// branch-free fast_tanh, and the fp32 div by v_rcp_f32. All state in
// registers; DPP reductions; depth-4 hc prefetch ring; no barriers.
__global__ __launch_bounds__(64, 1)
void attn_kernel(const float* __restrict__ w_t, const float* __restrict__ hcomb,
                 float* __restrict__ out) {
  const int b = blockIdx.x;
  const int l = threadIdx.x;          // 0..63
  const float* hrow = hcomb + (size_t)b * SS * HH2;

  __shared__ float tw_l[TMAXX];       // tw[t] history (final attn_w only)

  const float4 w1a = *(const float4*)(w_t + 4 * l);
  const float4 w1b = *(const float4*)(w_t + HH + 4 * l);
  const float4 w2a = *(const float4*)(w_t + HH2 + 4 * l);
  const float4 w2b = *(const float4*)(w_t + HH2 + HH + 4 * l);

  float t5v[5] = {0.f, -1e30f, -1e30f, -1e30f, -1e30f};
  int   t5s[5] = {0, 1, 2, 3, 4};
  int   t5cnt  = 1;                   // entry 0 = (t=0, zero row)
  float4 z4 = make_float4(0.f, 0.f, 0.f, 0.f);
  float4 sA0 = z4, sA1 = z4, sA2 = z4, sA3 = z4, sA4 = z4;
  float4 sB0 = z4, sB1 = z4, sB2 = z4, sB3 = z4, sB4 = z4;
  if (l == 0) tw_l[0] = 0.f;

  float tw5 = 0.f, inv = 0.f;

  // prefetch ring, depth 4 (SS % 4 == 0; all indexing static)
  float4 a0 = *(const float4*)(hrow + 0 * HH2 + 4 * l);
  float4 b0 = *(const float4*)(hrow + 0 * HH2 + HH + 4 * l);
  float4 a1 = *(const float4*)(hrow + 1 * HH2 + 4 * l);
  float4 b1 = *(const float4*)(hrow + 1 * HH2 + HH + 4 * l);
  float4 a2 = *(const float4*)(hrow + 2 * HH2 + 4 * l);
  float4 b2 = *(const float4*)(hrow + 2 * HH2 + HH + 4 * l);
  float4 a3 = *(const float4*)(hrow + 3 * HH2 + 4 * l);
  float4 b3 = *(const float4*)(hrow + 3 * HH2 + HH + 4 * l);

  auto step = [&](float4& ha, float4& hb, int i) {
    // ---- per-rank weights (uniform across lanes)
    float wr[5];
    if (i >= NTOP) {
      tw5 = t5v[4];
      float rk0 = fmaxf(t5v[0] - tw5 - EPSF, 0.f);
      float rk1 = fmaxf(t5v[1] - tw5 - EPSF, 0.f);
      float rk2 = fmaxf(t5v[2] - tw5 - EPSF, 0.f);
      float rk3 = fmaxf(t5v[3] - tw5 - EPSF, 0.f);
      inv = __builtin_amdgcn_rcpf(rk0 + rk1 + rk2 + rk3 + EPSF);
      wr[0] = rk0 * inv; wr[1] = rk1 * inv; wr[2] = rk2 * inv; wr[3] = rk3 * inv;
      wr[4] = 0.f;
    } else {
      float sv = fast_tanh(ha.x) * w1a.x + fast_tanh(ha.y) * w1a.y +
                 fast_tanh(ha.z) * w1a.z + fast_tanh(ha.w) * w1a.w +
                 fast_tanh(hb.x) * w1b.x + fast_tanh(hb.y) * w1b.y +
                 fast_tanh(hb.z) * w1b.z + fast_tanh(hb.w) * w1b.w;
      float s = dpp_sum64(sv);
#pragma unroll
      for (int k = 0; k < 5; ++k) wr[k] = (k < t5cnt) ? (s + t5v[k]) : 0.f;
    }
    // ---- rank -> slot weights (uniform, branch-free)
    float ws0 = 0.f, ws1 = 0.f, ws2 = 0.f, ws3 = 0.f, ws4 = 0.f;
#pragma unroll
    for (int k = 0; k < 5; ++k) {
      float wv = wr[k]; int s2 = t5s[k];
      ws0 += (s2 == 0) ? wv : 0.f;
      ws1 += (s2 == 1) ? wv : 0.f;
      ws2 += (s2 == 2) ? wv : 0.f;
      ws3 += (s2 == 3) ? wv : 0.f;
      ws4 += (s2 == 4) ? wv : 0.f;
    }
    // ---- attention context from register slot cache
    float4 cxA, cxB;
    cxA.x = ws0*sA0.x + ws1*sA1.x + ws2*sA2.x + ws3*sA3.x + ws4*sA4.x;
    cxA.y = ws0*sA0.y + ws1*sA1.y + ws2*sA2.y + ws3*sA3.y + ws4*sA4.y;
    cxA.z = ws0*sA0.z + ws1*sA1.z + ws2*sA2.z + ws3*sA3.z + ws4*sA4.z;
    cxA.w = ws0*sA0.w + ws1*sA1.w + ws2*sA2.w + ws3*sA3.w + ws4*sA4.w;
    cxB.x = ws0*sB0.x + ws1*sB1.x + ws2*sB2.x + ws3*sB3.x + ws4*sB4.x;
    cxB.y = ws0*sB0.y + ws1*sB1.y + ws2*sB2.y + ws3*sB3.y + ws4*sB4.y;
    cxB.z = ws0*sB0.z + ws1*sB1.z + ws2*sB2.z + ws3*sB3.z + ws4*sB4.z;
    cxB.w = ws0*sB0.w + ws1*sB1.w + ws2*sB2.w + ws3*sB3.w + ws4*sB4.w;
    // ---- h_new and v = tanh(h_new).w2
    float4 hnA, hnB;
    hnA.x = ha.x + cxA.x; hnA.y = ha.y + cxA.y; hnA.z = ha.z + cxA.z; hnA.w = ha.w + cxA.w;
    hnB.x = hb.x + cxB.x; hnB.y = hb.y + cxB.y; hnB.z = hb.z + cxB.z; hnB.w = hb.w + cxB.w;
    float pv = fast_tanh(hnA.x) * w2a.x + fast_tanh(hnA.y) * w2a.y +
               fast_tanh(hnA.z) * w2a.z + fast_tanh(hnA.w) * w2a.w +
               fast_tanh(hnB.x) * w2b.x + fast_tanh(hnB.y) * w2b.y +
               fast_tanh(hnB.z) * w2b.z + fast_tanh(hnB.w) * w2b.w;
    float v = dpp_sum64(pv);
    if (l == 0) tw_l[i + 1] = v;
    // ---- outputs at the last step (i = SS-1 is sparse: tw5/inv valid)
    if (i == SS - 1) {
      *(float4*)(out + (size_t)b * HH2 + 4 * l)      = cxA;
      *(float4*)(out + (size_t)b * HH2 + HH + 4 * l) = cxB;
      float* ow = out + (size_t)BB * HH2 + (size_t)b * SS;
#pragma unroll
      for (int j = 0; j < 8; ++j) {
        int t = j * 64 + l;
        float rr = tw_l[t] - tw5 - EPSF;
        ow[t] = rr > 0.f ? rr * inv : 0.f;
      }
      return;
    }
    // ---- replicated top-5 insert (uniform); update slot cache
    bool full = (t5cnt >= 5);
    bool ins  = !full || (v > t5v[4]);
    if (ins) {
      int p    = full ? 4 : t5cnt;
      int slot = full ? t5s[4] : t5cnt;
#pragma unroll
      for (int k = 0; k < 5; ++k) if (k == p) { t5v[k] = v; t5s[k] = slot; }
      if (slot == 0)      { sA0 = hnA; sB0 = hnB; }
      else if (slot == 1) { sA1 = hnA; sB1 = hnB; }
      else if (slot == 2) { sA2 = hnA; sB2 = hnB; }
      else if (slot == 3) { sA3 = hnA; sB3 = hnB; }
      else                { sA4 = hnA; sB4 = hnB; }
      if (!full) ++t5cnt;
#pragma unroll
      for (int k = 4; k >= 1; --k) {
        bool sw = (k <= p) && (t5v[k] > t5v[k - 1]);
        float v0 = t5v[k - 1], v1 = t5v[k];
        int   s0 = t5s[k - 1], s1 = t5s[k];
        t5v[k] = sw ? v0 : v1;  t5v[k - 1] = sw ? v1 : v0;
        t5s[k] = sw ? s0 : s1;  t5s[k - 1] = sw ? s1 : s0;
      }
    }
    // ---- prefetch step i+4 into this buffer (3 steps of slack)
    if (i + 4 < SS) {
      ha = *(const float4*)(hrow + (size_t)(i + 4) * HH2 + 4 * l);
      hb = *(const float4*)(hrow + (size_t)(i + 4) * HH2 + HH + 4 * l);
    }
  };

  for (int i = 0; i < SS; i += 4) {
    step(a0, b0, i);
    step(a1, b1, i + 1);
    step(a2, b2, i + 2);
    step(a3, b3, i + 3);
  }
}

// -------------------------------------------------------------------------
extern "C" void kernel_launch(void* const* d_in, const int* in_sizes, int n_in,
                              void* d_out, int out_size, void* d_ws, size_t ws_size,
                              hipStream_t stream) {
  const float* x     = (const float*)d_in[0];
  const float* Wih_f = (const float*)d_in[1];
  const float* Whh_f = (const float*)d_in[2];
  const float* b_f   = (const float*)d_in[3];
  const float* Wih_b = (const float*)d_in[4];
  const float* Whh_b = (const float*)d_in[5];
  const float* b_b   = (const float*)d_in[6];
  const float* w_t   = (const float*)d_in[7];
  float* out = (float*)d_out;

  char* ws = (char*)d_ws;
  uint4*  wq     = (uint4*)ws;                      // 512 KB int8 weights
  float*  scales = (float*)(ws + (1 << 20));        // 8 KB
  float*  hcomb  = (float*)(ws + (4 << 20));        // 64 MB

  init_kernel<<<8, 256, 0, stream>>>(Whh_f, Whh_b, wq, scales);
  lstm_kernel<<<2 * BB, 256, 0, stream>>>(x, Wih_f, b_f, Wih_b, b_b,
                                          wq, scales, hcomb);
  attn_kernel<<<BB, 64, 0, stream>>>(w_t, hcomb, out);
}